// Round 3
// baseline (138.461 us; speedup 1.0000x reference)
//
#include <hip/hip_runtime.h>

#define NBATCH 4096
#define SEQ 512
#define HID 5
#define NEMB 64

typedef float f2 __attribute__((ext_vector_type(2)));

__device__ __forceinline__ float fexp2(float x){ return __builtin_amdgcn_exp2f(x); }
__device__ __forceinline__ float frcp(float x){ return __builtin_amdgcn_rcpf(x); }
__device__ __forceinline__ f2 fma2(f2 a, f2 b, f2 c){ return __builtin_elementwise_fma(a, b, c); }

// broadcast lane j of each 4-lane quad to the whole quad (VALU DPP, no LDS pipe)
#define DPPB(v, CTRL) __int_as_float(__builtin_amdgcn_update_dpp(0, __float_as_int(v), (CTRL), 0xF, 0xF, true))

__global__ __launch_bounds__(64) void lstm_enc_kernel(
    const float* __restrict__ x_num, const int* __restrict__ x_cat,
    const float* __restrict__ embed, const float* __restrict__ W_ih,
    const float* __restrict__ W_hh, const float* __restrict__ b_ih,
    const float* __restrict__ b_hh, float* __restrict__ out)
{
    __shared__ float4 s_emb[NEMB];
    int tid = threadIdx.x;
    s_emb[tid] = ((const float4*)embed)[tid];
    __syncthreads();

    int gid = blockIdx.x * 64 + tid;
    int b   = gid >> 2;      // batch element (4 lanes per element)
    int sub = tid & 3;       // lane within quad == hidden unit owned (0..3)

    const float L2E = 1.4426950408889634f;
    // per-gate prescale: sigmoid gates -log2e; tanh gate -2*log2e (for 2*sigma(2x)-1 form)
    const float sc[4] = {-L2E, -L2E, -2.0f * L2E, -L2E};

    // own-unit weights (unit=sub) and unit-4 weights, gate-pairs (i,f) and (g,o)
    f2 wi[2][5], wh[2][5], bb[2];
    f2 wi4[2][5], wh4[2][5], bb4[2];
#pragma unroll
    for (int p = 0; p < 2; ++p) {
        int qa = 2 * p, qb = 2 * p + 1;
#pragma unroll
        for (int d = 0; d < 5; ++d) {
            wi[p][d]  = f2{W_ih[(qa * HID + sub) * 5 + d] * sc[qa],
                           W_ih[(qb * HID + sub) * 5 + d] * sc[qb]};
            wh[p][d]  = f2{W_hh[(qa * HID + sub) * HID + d] * sc[qa],
                           W_hh[(qb * HID + sub) * HID + d] * sc[qb]};
            wi4[p][d] = f2{W_ih[(qa * HID + 4) * 5 + d] * sc[qa],
                           W_ih[(qb * HID + 4) * 5 + d] * sc[qb]};
            wh4[p][d] = f2{W_hh[(qa * HID + 4) * HID + d] * sc[qa],
                           W_hh[(qb * HID + 4) * HID + d] * sc[qb]};
        }
        bb[p]  = f2{(b_ih[qa * HID + sub] + b_hh[qa * HID + sub]) * sc[qa],
                    (b_ih[qb * HID + sub] + b_hh[qb * HID + sub]) * sc[qb]};
        bb4[p] = f2{(b_ih[qa * HID + 4] + b_hh[qa * HID + 4]) * sc[qa],
                    (b_ih[qb * HID + 4] + b_hh[qb * HID + 4]) * sc[qb]};
    }

    const float4* xp = (const float4*)(x_num + (size_t)b * SEQ);
    const int4*   cp = (const int4*)(x_cat + (size_t)b * SEQ);
    float* outp = out + (size_t)b * SEQ * HID;

    float h = 0.0f, c = 0.0f, h4 = 0.0f, c4 = 0.0f;
    float hb0 = 0.f, hb1 = 0.f, hb2 = 0.f, hb3 = 0.f;

    float4 xf = xp[0];
    int4   cf = cp[0];
    float4 ec_[4];
    ec_[0] = s_emb[cf.x]; ec_[1] = s_emb[cf.y];
    ec_[2] = s_emb[cf.z]; ec_[3] = s_emb[cf.w];

    for (int t0 = 0; t0 < SEQ; t0 += 4) {
        int nidx = (t0 + 4 < SEQ) ? ((t0 >> 2) + 1) : 0;
        float4 xf_n = xp[nidx];
        int4   cf_n = cp[nidx];

        float xn_a[4] = {xf.x, xf.y, xf.z, xf.w};

        // off-chain: bias + x + emb contribution for all 4 steps, own unit + unit 4
        f2 xaO[4][2], xa4[4][2];
#pragma unroll
        for (int u = 0; u < 4; ++u) {
            float4 e = ec_[u];
            f2 xs  = {xn_a[u], xn_a[u]};
            f2 e0  = {e.x, e.x};
            f2 e1  = {e.y, e.y};
            f2 e2  = {e.z, e.z};
            f2 e3  = {e.w, e.w};
#pragma unroll
            for (int p = 0; p < 2; ++p) {
                f2 a = fma2(xs, wi[p][0], bb[p]);
                a = fma2(e0, wi[p][1], a);
                a = fma2(e1, wi[p][2], a);
                a = fma2(e2, wi[p][3], a);
                a = fma2(e3, wi[p][4], a);
                xaO[u][p] = a;
                f2 a4 = fma2(xs, wi4[p][0], bb4[p]);
                a4 = fma2(e0, wi4[p][1], a4);
                a4 = fma2(e1, wi4[p][2], a4);
                a4 = fma2(e2, wi4[p][3], a4);
                a4 = fma2(e3, wi4[p][4], a4);
                xa4[u][p] = a4;
            }
        }

#pragma unroll
        for (int u = 0; u < 4; ++u) {
            f2 aO0 = xaO[u][0], aO1 = xaO[u][1];
            f2 a40 = xa4[u][0], a41 = xa4[u][1];

            f2 s0 = {hb0, hb0};
            f2 s1 = {hb1, hb1};
            f2 s2 = {hb2, hb2};
            f2 s3 = {hb3, hb3};
            f2 s4 = {h4, h4};

            aO0 = fma2(s0, wh[0][0], aO0);  aO1 = fma2(s0, wh[1][0], aO1);
            a40 = fma2(s0, wh4[0][0], a40); a41 = fma2(s0, wh4[1][0], a41);
            aO0 = fma2(s1, wh[0][1], aO0);  aO1 = fma2(s1, wh[1][1], aO1);
            a40 = fma2(s1, wh4[0][1], a40); a41 = fma2(s1, wh4[1][1], a41);
            aO0 = fma2(s2, wh[0][2], aO0);  aO1 = fma2(s2, wh[1][2], aO1);
            a40 = fma2(s2, wh4[0][2], a40); a41 = fma2(s2, wh4[1][2], a41);
            aO0 = fma2(s3, wh[0][3], aO0);  aO1 = fma2(s3, wh[1][3], aO1);
            a40 = fma2(s3, wh4[0][3], a40); a41 = fma2(s3, wh4[1][3], a41);
            aO0 = fma2(s4, wh[0][4], aO0);  aO1 = fma2(s4, wh[1][4], aO1);
            a40 = fma2(s4, wh4[0][4], a40); a41 = fma2(s4, wh4[1][4], a41);

            // activations: sigmoid = rcp(1+exp2(a)); tanh = 2*rcp(1+exp2(a)) - 1
            float iv = frcp(1.0f + fexp2(aO0.x));
            float fv = frcp(1.0f + fexp2(aO0.y));
            float gv = fmaf(frcp(1.0f + fexp2(aO1.x)), 2.0f, -1.0f);
            float ov = frcp(1.0f + fexp2(aO1.y));
            float i4 = frcp(1.0f + fexp2(a40.x));
            float f4 = frcp(1.0f + fexp2(a40.y));
            float g4 = fmaf(frcp(1.0f + fexp2(a41.x)), 2.0f, -1.0f);
            float o4 = frcp(1.0f + fexp2(a41.y));

            c  = fmaf(fv, c,  iv * gv);
            c4 = fmaf(f4, c4, i4 * g4);

            float tc = fmaf(frcp(1.0f + fexp2(c  * (-2.0f * L2E))), 2.0f, -1.0f);
            float t4 = fmaf(frcp(1.0f + fexp2(c4 * (-2.0f * L2E))), 2.0f, -1.0f);
            h  = ov * tc;
            h4 = o4 * t4;

            // broadcast h of lanes 0..3 to the quad for the next step (VALU DPP)
            hb0 = DPPB(h, 0x00);
            hb1 = DPPB(h, 0x55);
            hb2 = DPPB(h, 0xAA);
            hb3 = DPPB(h, 0xFF);

            outp[(t0 + u) * HID + sub] = h;
            if (sub == 0) outp[(t0 + u) * HID + 4] = h4;
        }

        ec_[0] = s_emb[cf_n.x]; ec_[1] = s_emb[cf_n.y];
        ec_[2] = s_emb[cf_n.z]; ec_[3] = s_emb[cf_n.w];
        xf = xf_n;
    }

    {
        size_t base = (size_t)NBATCH * SEQ * HID;
        out[base + (size_t)b * HID + sub] = h;                           // hT
        out[base + (size_t)NBATCH * HID + (size_t)b * HID + sub] = c;    // cT
        if (sub == 0) {
            out[base + (size_t)b * HID + 4] = h4;
            out[base + (size_t)NBATCH * HID + (size_t)b * HID + 4] = c4;
        }
    }
}

extern "C" void kernel_launch(void* const* d_in, const int* in_sizes, int n_in,
                              void* d_out, int out_size, void* d_ws, size_t ws_size,
                              hipStream_t stream) {
    const float* x_num = (const float*)d_in[0];
    const int*   x_cat = (const int*)d_in[1];
    const float* embed = (const float*)d_in[2];
    const float* W_ih  = (const float*)d_in[3];
    const float* W_hh  = (const float*)d_in[4];
    const float* b_ih  = (const float*)d_in[5];
    const float* b_hh  = (const float*)d_in[6];
    float* out = (float*)d_out;

    dim3 grid(NBATCH * 4 / 64);  // 256 blocks, 1 wave each
    dim3 block(64);
    hipLaunchKernelGGL(lstm_enc_kernel, grid, block, 0, stream,
                       x_num, x_cat, embed, W_ih, W_hh, b_ih, b_hh, out);
}

// Round 5
// 109.006 us; speedup vs baseline: 1.2702x; 1.2702x over previous
//
#include <hip/hip_runtime.h>

#define NBATCH 4096
#define SEQ 512
#define HID 5
#define NEMB 64

__device__ __forceinline__ float fexp2(float x){ return __builtin_amdgcn_exp2f(x); }
__device__ __forceinline__ float frcp(float x){ return __builtin_amdgcn_rcpf(x); }

// quad_perm broadcast: every lane of each quad takes quad-lane j (bound_ctrl, full masks)
#define DPPQ(v, j) __int_as_float(__builtin_amdgcn_update_dpp(0, __float_as_int(v), ((j) * 0x55), 0xF, 0xF, true))
// masked DPP move: lanes in BANKS get src shifted by CTRL, others keep `old`
#define DPPM(old, src, CTRL, BANKS) __int_as_float(__builtin_amdgcn_update_dpp(__float_as_int(old), __float_as_int(src), (CTRL), 0xF, (BANKS), false))
#define ROW_SHL4 0x104  /* lane i reads lane i+4 */
#define ROW_SHR4 0x114  /* lane i reads lane i-4 */

__global__ __launch_bounds__(64) void lstm_enc_kernel(
    const float* __restrict__ x_num, const int* __restrict__ x_cat,
    const float* __restrict__ embed, const float* __restrict__ W_ih,
    const float* __restrict__ W_hh, const float* __restrict__ b_ih,
    const float* __restrict__ b_hh, float* __restrict__ out)
{
    __shared__ float4 s_emb[NEMB];
    int tid = threadIdx.x;
    s_emb[tid] = ((const float4*)embed)[tid];
    __syncthreads();

    int gid = blockIdx.x * 64 + tid;
    int b   = gid >> 3;         // batch element (8 lanes per element)
    int sub = tid & 7;          // lane within group
    int k   = (sub < HID) ? sub : (HID - 1);  // lanes 4..7 ALL carry unit 4
    bool active = (sub < HID);

    const float L2E = 1.4426950408889634f;
    // prescale: sigmoid gates (i,f,o) by -log2e; tanh gate (g) by -2*log2e (2*sigma-1 form)
    const float sc[4] = {-L2E, -L2E, -2.0f * L2E, -L2E};

    float wi[4][5], wh[4][5], bb[4];
#pragma unroll
    for (int q = 0; q < 4; ++q) {
        float s = sc[q];
        int g = q * HID + k;
#pragma unroll
        for (int d = 0; d < 5; ++d) {
            wi[q][d] = W_ih[g * 5 + d] * s;
            wh[q][d] = W_hh[g * HID + d] * s;
        }
        bb[q] = (b_ih[g] + b_hh[g]) * s;
    }

    const float4* xp = (const float4*)(x_num + (size_t)b * SEQ);
    const int4*   cp = (const int4*)(x_cat + (size_t)b * SEQ);
    float* outp = out + (size_t)b * SEQ * HID + k;

    float h = 0.0f, c = 0.0f;

    float4 xf = xp[0];
    int4   cf = cp[0];
    float4 ec_[4];
    ec_[0] = s_emb[cf.x]; ec_[1] = s_emb[cf.y];
    ec_[2] = s_emb[cf.z]; ec_[3] = s_emb[cf.w];

    for (int t0 = 0; t0 < SEQ; t0 += 4) {
        int nidx = (t0 + 4 < SEQ) ? ((t0 >> 2) + 1) : 0;
        float4 xf_n = xp[nidx];
        int4   cf_n = cp[nidx];

        float xn_a[4] = {xf.x, xf.y, xf.z, xf.w};

        // off-chain: bias + x + emb part for all 4 steps
        float xa[4][4];
#pragma unroll
        for (int u = 0; u < 4; ++u) {
            float4 e = ec_[u];
#pragma unroll
            for (int q = 0; q < 4; ++q) {
                float a = fmaf(xn_a[u], wi[q][0], bb[q]);
                a = fmaf(e.x, wi[q][1], a);
                a = fmaf(e.y, wi[q][2], a);
                a = fmaf(e.z, wi[q][3], a);
                a = fmaf(e.w, wi[q][4], a);
                xa[u][q] = a;
            }
        }

#pragma unroll
        for (int u = 0; u < 4; ++u) {
            // pure-VALU broadcast of h0..h4 across each 8-lane group.
            // quadA (lanes 0-3) holds h0..h3; quadB (lanes 4-7) all hold h4.
            float q0 = DPPQ(h, 0);
            float q1 = DPPQ(h, 1);
            float q2 = DPPQ(h, 2);
            float q3 = DPPQ(h, 3);
            float hb0 = DPPM(q0, q0, ROW_SHR4, 0xA);  // quadB pulls quadA's value
            float hb1 = DPPM(q1, q1, ROW_SHR4, 0xA);
            float hb2 = DPPM(q2, q2, ROW_SHR4, 0xA);
            float hb3 = DPPM(q3, q3, ROW_SHR4, 0xA);
            float hb4 = DPPM(h,  h,  ROW_SHL4, 0x5);  // quadA pulls h4; quadB keeps own h(=h4)

            float a0 = xa[u][0], a1 = xa[u][1], a2 = xa[u][2], a3 = xa[u][3];
            a0 = fmaf(hb0, wh[0][0], a0);
            a1 = fmaf(hb0, wh[1][0], a1);
            a2 = fmaf(hb0, wh[2][0], a2);
            a3 = fmaf(hb0, wh[3][0], a3);
            a0 = fmaf(hb1, wh[0][1], a0);
            a1 = fmaf(hb1, wh[1][1], a1);
            a2 = fmaf(hb1, wh[2][1], a2);
            a3 = fmaf(hb1, wh[3][1], a3);
            a0 = fmaf(hb2, wh[0][2], a0);
            a1 = fmaf(hb2, wh[1][2], a1);
            a2 = fmaf(hb2, wh[2][2], a2);
            a3 = fmaf(hb2, wh[3][2], a3);
            a0 = fmaf(hb3, wh[0][3], a0);
            a1 = fmaf(hb3, wh[1][3], a1);
            a2 = fmaf(hb3, wh[2][3], a2);
            a3 = fmaf(hb3, wh[3][3], a3);
            a0 = fmaf(hb4, wh[0][4], a0);
            a1 = fmaf(hb4, wh[1][4], a1);
            a2 = fmaf(hb4, wh[2][4], a2);
            a3 = fmaf(hb4, wh[3][4], a3);

            // sigma = rcp(1+exp2(a)) [a prescaled -log2e]; tanh = 2*rcp(1+exp2(a)) - 1 [a prescaled -2log2e]
            float iv = frcp(1.0f + fexp2(a0));
            float fv = frcp(1.0f + fexp2(a1));
            float gv = fmaf(frcp(1.0f + fexp2(a2)), 2.0f, -1.0f);
            float ov = frcp(1.0f + fexp2(a3));

            c = fmaf(fv, c, iv * gv);
            float tc = fmaf(frcp(1.0f + fexp2(c * (-2.0f * L2E))), 2.0f, -1.0f);
            h = ov * tc;

            if (active) outp[(t0 + u) * HID] = h;
        }

        ec_[0] = s_emb[cf_n.x]; ec_[1] = s_emb[cf_n.y];
        ec_[2] = s_emb[cf_n.z]; ec_[3] = s_emb[cf_n.w];
        xf = xf_n;
    }

    if (active) {
        size_t base = (size_t)NBATCH * SEQ * HID;
        out[base + (size_t)b * HID + k] = h;                          // hT
        out[base + (size_t)NBATCH * HID + (size_t)b * HID + k] = c;   // cT
    }
}

extern "C" void kernel_launch(void* const* d_in, const int* in_sizes, int n_in,
                              void* d_out, int out_size, void* d_ws, size_t ws_size,
                              hipStream_t stream) {
    const float* x_num = (const float*)d_in[0];
    const int*   x_cat = (const int*)d_in[1];
    const float* embed = (const float*)d_in[2];
    const float* W_ih  = (const float*)d_in[3];
    const float* W_hh  = (const float*)d_in[4];
    const float* b_ih  = (const float*)d_in[5];
    const float* b_hh  = (const float*)d_in[6];
    float* out = (float*)d_out;

    dim3 grid(NBATCH * 8 / 64);  // 512 blocks, 1 wave each
    dim3 block(64);
    hipLaunchKernelGGL(lstm_enc_kernel, grid, block, 0, stream,
                       x_num, x_cat, embed, W_ih, W_hh, b_ih, b_hh, out);
}

// Round 6
// 89.444 us; speedup vs baseline: 1.5480x; 1.2187x over previous
//
#include <hip/hip_runtime.h>

#define NBATCH 4096
#define SEQ 512
#define HID 5
#define NEMB 64

__device__ __forceinline__ float fexp2(float x){ return __builtin_amdgcn_exp2f(x); }
__device__ __forceinline__ float frcp(float x){ return __builtin_amdgcn_rcpf(x); }

// ds_swizzle BitMode (bit15=0): offset = (xor<<10)|(or<<5)|(and); and=0, or=4k
// -> every lane reads lane 4k within its 32-lane half
#define SWZ(v, k) __int_as_float(__builtin_amdgcn_ds_swizzle(__float_as_int(v), ((4*(k)) << 5)))
// quad_perm broadcast of quad-lane j to the whole quad
#define DPPQ(v, j) __int_as_float(__builtin_amdgcn_update_dpp(0, __float_as_int(v), ((j) * 0x55), 0xF, 0xF, true))

__global__ __launch_bounds__(64) void lstm_enc_kernel(
    const float* __restrict__ x_num, const int* __restrict__ x_cat,
    const float* __restrict__ embed, const float* __restrict__ W_ih,
    const float* __restrict__ W_hh, const float* __restrict__ b_ih,
    const float* __restrict__ b_hh, float* __restrict__ out)
{
    __shared__ float4 s_emb[NEMB];
    int tid = threadIdx.x;
    s_emb[tid] = ((const float4*)embed)[tid];
    __syncthreads();

    // layout: 2 batch elements per wave, one per 32-lane half.
    // within a half: lane l = 4*unit + gate (units 0..4 on quads 0..4, lanes 20..31 idle-dup unit 4)
    int half = tid >> 5;
    int l    = tid & 31;
    int b    = blockIdx.x * 2 + half;
    int k    = ((l >> 2) < HID) ? (l >> 2) : (HID - 1);
    int g    = l & 3;                       // 0:i 1:f 2:g 3:o
    bool st  = (l < 20) && (g == 0);        // storing lanes: l = 0,4,8,12,16 (h_k holder)

    const float L2E = 1.4426950408889634f;
    // prescale: sigmoid gates by -log2e; tanh gate by -2*log2e (tanh = 2*sigma-1)
    float s_  = (g == 2) ? (-2.0f * L2E) : (-L2E);
    float fm  = (g == 2) ? 2.0f : 1.0f;     // activation fixup: v = r*fm + fb
    float fb  = (g == 2) ? -1.0f : 0.0f;

    int row = g * HID + k;                  // row in W_ih/W_hh (gate-major, 20 rows)
    float wi_[5], wh_[5];
#pragma unroll
    for (int d = 0; d < 5; ++d) {
        wi_[d] = W_ih[row * 5 + d] * s_;
        wh_[d] = W_hh[row * 5 + d] * s_;
    }
    float bias = (b_ih[row] + b_hh[row]) * s_;

    const float4* xp = (const float4*)(x_num + (size_t)b * SEQ);
    const int4*   cp = (const int4*)(x_cat + (size_t)b * SEQ);
    float* outp = out + (size_t)b * SEQ * HID + k;

    float h = 0.f, c = 0.f;
    float hb0 = 0.f, hb1 = 0.f, hb2 = 0.f, hb3 = 0.f, hb4 = 0.f;

    float4 xf = xp[0];
    int4   cf = cp[0];
    float4 ec_[4];
    ec_[0] = s_emb[cf.x]; ec_[1] = s_emb[cf.y];
    ec_[2] = s_emb[cf.z]; ec_[3] = s_emb[cf.w];

    for (int t0 = 0; t0 < SEQ; t0 += 4) {
        int nidx = (t0 + 4 < SEQ) ? ((t0 >> 2) + 1) : 0;
        float4 xf_n = xp[nidx];
        int4   cf_n = cp[nidx];

        float xn_a[4] = {xf.x, xf.y, xf.z, xf.w};

        // off-chain: bias + x + emb part (one gate value per lane)
        float xa[4];
#pragma unroll
        for (int u = 0; u < 4; ++u) {
            float4 e = ec_[u];
            float a = fmaf(xn_a[u], wi_[0], bias);
            a = fmaf(e.x, wi_[1], a);
            a = fmaf(e.y, wi_[2], a);
            a = fmaf(e.z, wi_[3], a);
            a = fmaf(e.w, wi_[4], a);
            xa[u] = a;
        }

#pragma unroll
        for (int u = 0; u < 4; ++u) {
            // h-part: 5-FMA dot with broadcast h (per-lane gate row)
            float a = xa[u];
            a = fmaf(hb0, wh_[0], a);
            a = fmaf(hb1, wh_[1], a);
            a = fmaf(hb2, wh_[2], a);
            a = fmaf(hb3, wh_[3], a);
            a = fmaf(hb4, wh_[4], a);

            // ONE sigma per lane; tanh-gate lanes apply 2r-1 via per-lane consts
            float r = frcp(1.0f + fexp2(a));
            float v = fmaf(r, fm, fb);

            // gather i,f,g,o within the unit's quad (pure VALU)
            float ai = DPPQ(v, 0);
            float af = DPPQ(v, 1);
            float ag = DPPQ(v, 2);
            float ao = DPPQ(v, 3);

            // c,h computed redundantly on all 4 lanes of the quad
            c = fmaf(af, c, ai * ag);
            float tc = fmaf(frcp(1.0f + fexp2(c * (-2.0f * L2E))), 2.0f, -1.0f);
            h = ao * tc;

            // broadcast h_0..h_4 (lanes 0,4,8,12,16 of each half) for next step
            hb0 = SWZ(h, 0);
            hb1 = SWZ(h, 1);
            hb2 = SWZ(h, 2);
            hb3 = SWZ(h, 3);
            hb4 = SWZ(h, 4);

            if (st) outp[(t0 + u) * HID] = h;
        }

        ec_[0] = s_emb[cf_n.x]; ec_[1] = s_emb[cf_n.y];
        ec_[2] = s_emb[cf_n.z]; ec_[3] = s_emb[cf_n.w];
        xf = xf_n;
    }

    if (st) {
        size_t base = (size_t)NBATCH * SEQ * HID;
        out[base + (size_t)b * HID + k] = h;                          // hT
        out[base + (size_t)NBATCH * HID + (size_t)b * HID + k] = c;   // cT
    }
}

extern "C" void kernel_launch(void* const* d_in, const int* in_sizes, int n_in,
                              void* d_out, int out_size, void* d_ws, size_t ws_size,
                              hipStream_t stream) {
    const float* x_num = (const float*)d_in[0];
    const int*   x_cat = (const int*)d_in[1];
    const float* embed = (const float*)d_in[2];
    const float* W_ih  = (const float*)d_in[3];
    const float* W_hh  = (const float*)d_in[4];
    const float* b_ih  = (const float*)d_in[5];
    const float* b_hh  = (const float*)d_in[6];
    float* out = (float*)d_out;

    dim3 grid(NBATCH / 2);   // 2048 blocks, 1 wave each -> 2 waves/SIMD
    dim3 block(64);
    hipLaunchKernelGGL(lstm_enc_kernel, grid, block, 0, stream,
                       x_num, x_cat, embed, W_ih, W_hh, b_ih, b_hh, out);
}